// Round 6
// baseline (918.781 us; speedup 1.0000x reference)
//
#include <hip/hip_runtime.h>

#define RR 8
#define DF 128
#define NPW 8          // nodes per wave (A rows 0..7; rows 8..15 zero)
#define SCAN_B 1024

typedef __attribute__((ext_vector_type(4))) float f32x4;
typedef __attribute__((ext_vector_type(8))) short sv8;
typedef sv8 __attribute__((may_alias)) sv8a;

__device__ __forceinline__ unsigned short bf16r(float f) {
    uint32_t u = __float_as_uint(f);
    u += 0x7fffu + ((u >> 16) & 1u);   // round-to-nearest-even
    return (unsigned short)(u >> 16);
}
__device__ __forceinline__ uint32_t packbf(float lo, float hi) {
    return (uint32_t)bf16r(lo) | ((uint32_t)bf16r(hi) << 16);
}

// ---------------- CSR build (proven) ----------------
__global__ void count_kernel(const int* __restrict__ tgt, const int* __restrict__ et,
                             int* __restrict__ cnt, int E) {
    int e = blockIdx.x * blockDim.x + threadIdx.x;
    if (e < E) atomicAdd(&cnt[tgt[e] * RR + et[e]], 1);
}

__global__ void scan_local(const int* __restrict__ in, int* __restrict__ excl,
                           int* __restrict__ bsum, int n) {
    __shared__ int sm[2][SCAN_B];
    int base = blockIdx.x * SCAN_B;
    for (int t = threadIdx.x; t < SCAN_B; t += 256) {
        int idx = base + t;
        sm[0][t] = (idx < n) ? in[idx] : 0;
    }
    __syncthreads();
    int pin = 0;
    for (int off = 1; off < SCAN_B; off <<= 1) {
        for (int t = threadIdx.x; t < SCAN_B; t += 256) {
            int v = sm[pin][t];
            if (t >= off) v += sm[pin][t - off];
            sm[pin ^ 1][t] = v;
        }
        __syncthreads();
        pin ^= 1;
    }
    for (int t = threadIdx.x; t < SCAN_B; t += 256) {
        int idx = base + t;
        if (idx < n) excl[idx] = sm[pin][t] - in[idx];
    }
    if (threadIdx.x == 0) bsum[blockIdx.x] = sm[pin][SCAN_B - 1];
}

__global__ void scan_bsum(int* __restrict__ bsum, int nb) {
    __shared__ int sm[512];
    for (int t = threadIdx.x; t < nb; t += 256) sm[t] = bsum[t];
    __syncthreads();
    if (threadIdx.x == 0) {
        int run = 0;
        for (int i = 0; i < nb; ++i) { int v = sm[i]; sm[i] = run; run += v; }
    }
    __syncthreads();
    for (int t = threadIdx.x; t < nb; t += 256) bsum[t] = sm[t];
}

__global__ void scan_finish(int* __restrict__ rowptr, const int* __restrict__ bsum,
                            int* __restrict__ cursor, int n, int E) {
    int i = blockIdx.x * blockDim.x + threadIdx.x;
    if (i < n) {
        int v = rowptr[i] + bsum[i / SCAN_B];
        rowptr[i] = v;
        cursor[i] = v;
    }
    if (i == 0) rowptr[n] = E;
}

__global__ void fill_kernel(const int* __restrict__ src, const int* __restrict__ tgt,
                            const int* __restrict__ et, int* __restrict__ cursor,
                            int* __restrict__ es, int E) {
    int e = blockIdx.x * blockDim.x + threadIdx.x;
    if (e < E) {
        int seg = tgt[e] * RR + et[e];
        int pos = atomicAdd(&cursor[seg], 1);
        es[pos] = src[e];
    }
}

// ---------------- f32 [n,2t] -> bf16-pair u32 [n,t] ----------------
__global__ void pack_x_kernel(const float* __restrict__ x, uint32_t* __restrict__ xb,
                              int n64) {
    int t = blockIdx.x * blockDim.x + threadIdx.x;
    if (t < n64) xb[t] = packbf(x[2 * t], x[2 * t + 1]);
}

// ---------------- W packing into MFMA B-fragment order (proven) ----------------
__global__ void pack_w_kernel(const float* __restrict__ W, const float* __restrict__ root,
                              unsigned short* __restrict__ wp, int NT) {
    int tid = blockIdx.x * blockDim.x + threadIdx.x;
    int total = 9 * NT * 2048;
    if (tid >= total) return;
    int i = tid & 7;
    int lane = (tid >> 3) & 63;
    int kk = (tid >> 9) & 3;
    int t = (tid >> 11) % NT;
    int rel = (tid >> 11) / NT;
    int k = kk * 32 + ((lane >> 4) << 3) + i;
    int col = t * 16 + (lane & 15);
    int dout = NT * 16;
    float v = (rel < RR) ? W[((long)rel * DF + k) * dout + col] : root[(long)k * dout + col];
    wp[tid] = bf16r(v);
}

// ---------------- fused gather-mean + MFMA transform ----------------
// Identical structure to the passing round-5 kernel; the only change is the
// gather source: bf16-pair u32 rows (256B/row instead of 512B) to halve the
// L2-miss/L3 traffic the kernel is bandwidth-bound on. Unpack to f32 for the
// accumulate; A-tile/bias/epilogue unchanged.
template <int NT, bool RELU>
__global__ __launch_bounds__(256) void fused_mfma_kernel(
    const uint32_t* __restrict__ xb,       // [N,64] bf16-pairs
    const int* __restrict__ es,            // segment-sorted src
    const int* __restrict__ rowptr,        // [N*R+1]
    const unsigned short* __restrict__ wp, // packed W frags
    const float* __restrict__ bias,        // [NT*16]
    float* __restrict__ out, int N) {
    __shared__ uint32_t a_sm[4][16][68];   // 16 rows x 136 bf16, wave-private
    const int wave = threadIdx.x >> 6;
    const int lane = threadIdx.x & 63;
    const int nb = (blockIdx.x * 4 + wave) * NPW;
    if (nb >= N) return;
    uint32_t(*A)[68] = a_sm[wave];

    for (int z = lane; z < 8 * 68; z += 64) (&A[8][0])[z] = 0u;  // rows 8..15 = 0

    const int j = lane;                    // feature-pair slot
    const int arow = lane & 15;
    const int ag = lane >> 4;

    f32x4 acc[NT];
#pragma unroll
    for (int t = 0; t < NT; ++t) acc[t] = (f32x4){0.f, 0.f, 0.f, 0.f};

    for (int rel = 0; rel <= RR; ++rel) {
        if (rel < RR) {
            int e0[NPW], e1[NPW];
            int mx = 0;
#pragma unroll
            for (int m = 0; m < NPW; ++m) {
                int seg = (nb + m) * RR + rel;
                e0[m] = rowptr[seg];
                e1[m] = rowptr[seg + 1];
                int c = e1[m] - e0[m];
                mx = (c > mx) ? c : mx;
            }
            float sx[NPW], sy[NPW];
#pragma unroll
            for (int m = 0; m < NPW; ++m) { sx[m] = 0.f; sy[m] = 0.f; }

            if (mx > 0) {
                int s[NPW];
#pragma unroll
                for (int m = 0; m < NPW; ++m) {
                    int hi = e1[m] - 1; hi = (hi < 0) ? 0 : hi;
                    int idx = (e0[m] < hi) ? e0[m] : hi;
                    s[m] = es[idx];
                }
                for (int it = 0; it < mx; ++it) {
                    int sn[NPW];
#pragma unroll
                    for (int m = 0; m < NPW; ++m) {   // prefetch next iteration
                        int idx = e0[m] + it + 1;
                        int hi = e1[m] - 1; hi = (hi < 0) ? 0 : hi;
                        idx = (idx < hi) ? idx : hi;
                        sn[m] = es[idx];
                    }
#pragma unroll
                    for (int m = 0; m < NPW; ++m) {   // 8 gathers in flight
                        uint32_t u = xb[s[m] * 64 + j];
                        bool v = (e0[m] + it) < e1[m];
                        sx[m] += v ? __uint_as_float(u << 16) : 0.f;
                        sy[m] += v ? __uint_as_float(u & 0xffff0000u) : 0.f;
                    }
#pragma unroll
                    for (int m = 0; m < NPW; ++m) s[m] = sn[m];
                }
            }
#pragma unroll
            for (int m = 0; m < NPW; ++m) {
                float inv = 1.f / fmaxf((float)(e1[m] - e0[m]), 1.f);
                A[m][j] = packbf(sx[m] * inv, sy[m] * inv);
            }
        } else {
            // root "relation": A = raw input features (already bf16 pairs)
            for (int m = 0; m < NPW; ++m) A[m][j] = xb[(nb + m) * 64 + j];
        }
        asm volatile("" ::: "memory");   // pin staging-writes before frag-reads
        sv8 af[4];                        // lane: A[arow][kk*32 + ag*8 .. +7]
#pragma unroll
        for (int kk = 0; kk < 4; ++kk)
            af[kk] = *(const sv8a*)&A[arow][kk * 16 + ag * 4];
        asm volatile("" ::: "memory");   // pin frag-reads before next staging
        const unsigned short* wr = wp + ((long)rel * NT << 11);
#pragma unroll
        for (int t = 0; t < NT; ++t) {
#pragma unroll
            for (int kk = 0; kk < 4; ++kk) {
                sv8 bf = *(const sv8a*)(wr + (((t * 4 + kk) << 9) + (lane << 3)));
                acc[t] = __builtin_amdgcn_mfma_f32_16x16x32_bf16(af[kk], bf, acc[t], 0, 0, 0);
            }
        }
    }

    // ---- epilogue: direct global stores (C/D map: col=lane&15, row=4*(lane>>4)+reg)
    constexpr int DOUT = NT * 16;
    if (lane < 32) {
#pragma unroll
        for (int t = 0; t < NT; ++t) {
            int col = t * 16 + (lane & 15);
            float bv = bias[col];
#pragma unroll
            for (int reg = 0; reg < 4; ++reg) {
                int row = ((lane >> 4) << 2) + reg;   // 0..7
                float v = acc[t][reg] + bv;
                if (RELU) v = fmaxf(v, 0.f);
                out[(long)(nb + row) * DOUT + col] = v;
            }
        }
    }
}

extern "C" void kernel_launch(void* const* d_in, const int* in_sizes, int n_in,
                              void* d_out, int out_size, void* d_ws, size_t ws_size,
                              hipStream_t stream) {
    const float* xf = (const float*)d_in[0];
    const float* W1 = (const float*)d_in[1];
    const float* r1 = (const float*)d_in[2];
    const float* b1 = (const float*)d_in[3];
    const float* W2 = (const float*)d_in[4];
    const float* r2 = (const float*)d_in[5];
    const float* b2 = (const float*)d_in[6];
    const int* eidx = (const int*)d_in[7];
    const int* etyp = (const int*)d_in[8];
    const int N = in_sizes[0] / DF;
    const int E = in_sizes[8];
    const int* src = eidx;
    const int* tgt = eidx + E;
    const int NR = N * RR;

    // ws: cnt[NR] rowptr[NR+16] cursor[NR+16] bsum[512] es[E]
    //     x1f[N*128]f32 xb[N*64]u32 x1b[N*64]u32 wp1 wp2
    int* cnt = (int*)d_ws;
    int* rowptr = cnt + NR;
    int* cursor = rowptr + NR + 16;
    int* bsum = cursor + NR + 16;
    int* es = bsum + 512;
    float* x1f = (float*)(es + E);
    uint32_t* xb = (uint32_t*)(x1f + (size_t)N * DF);
    uint32_t* x1b = xb + (size_t)N * 64;
    unsigned short* wp1 = (unsigned short*)(x1b + (size_t)N * 64);
    unsigned short* wp2 = wp1 + 9 * 8 * 2048;

    const int nb1 = (NR + SCAN_B - 1) / SCAN_B;

    hipMemsetAsync(cnt, 0, (size_t)NR * sizeof(int), stream);
    count_kernel<<<(E + 255) / 256, 256, 0, stream>>>(tgt, etyp, cnt, E);
    scan_local<<<nb1, 256, 0, stream>>>(cnt, rowptr, bsum, NR);
    scan_bsum<<<1, 256, 0, stream>>>(bsum, nb1);
    scan_finish<<<(NR + 255) / 256, 256, 0, stream>>>(rowptr, bsum, cursor, NR, E);
    fill_kernel<<<(E + 255) / 256, 256, 0, stream>>>(src, tgt, etyp, cursor, es, E);

    pack_x_kernel<<<(N * 64 + 255) / 256, 256, 0, stream>>>(xf, xb, N * 64);
    pack_w_kernel<<<(9 * 8 * 2048 + 255) / 256, 256, 0, stream>>>(W1, r1, wp1, 8);
    pack_w_kernel<<<(9 * 4 * 2048 + 255) / 256, 256, 0, stream>>>(W2, r2, wp2, 4);

    const int fblocks = (N / NPW + 3) / 4;
    fused_mfma_kernel<8, true><<<fblocks, 256, 0, stream>>>(
        xb, es, rowptr, wp1, b1, x1f, N);
    pack_x_kernel<<<(N * 64 + 255) / 256, 256, 0, stream>>>(x1f, x1b, N * 64);
    fused_mfma_kernel<4, false><<<fblocks, 256, 0, stream>>>(
        x1b, es, rowptr, wp2, b2, (float*)d_out, N);
}

// Round 7
// 704.971 us; speedup vs baseline: 1.3033x; 1.3033x over previous
//
#include <hip/hip_runtime.h>

#define RR 8
#define DF 128
#define NPW 8          // nodes per wave (A rows 0..7; rows 8..15 zero)
#define SCAN_B 1024

typedef __attribute__((ext_vector_type(4))) float f32x4;
typedef __attribute__((ext_vector_type(8))) short sv8;
typedef sv8 __attribute__((may_alias)) sv8a;

__device__ __forceinline__ unsigned short bf16r(float f) {
    uint32_t u = __float_as_uint(f);
    u += 0x7fffu + ((u >> 16) & 1u);   // round-to-nearest-even
    return (unsigned short)(u >> 16);
}
__device__ __forceinline__ uint32_t packbf(float lo, float hi) {
    return (uint32_t)bf16r(lo) | ((uint32_t)bf16r(hi) << 16);
}

// ---------------- CSR build (proven) ----------------
__global__ void count_kernel(const int* __restrict__ tgt, const int* __restrict__ et,
                             int* __restrict__ cnt, int E) {
    int e = blockIdx.x * blockDim.x + threadIdx.x;
    if (e < E) atomicAdd(&cnt[tgt[e] * RR + et[e]], 1);
}

__global__ void scan_local(const int* __restrict__ in, int* __restrict__ excl,
                           int* __restrict__ bsum, int n) {
    __shared__ int sm[2][SCAN_B];
    int base = blockIdx.x * SCAN_B;
    for (int t = threadIdx.x; t < SCAN_B; t += 256) {
        int idx = base + t;
        sm[0][t] = (idx < n) ? in[idx] : 0;
    }
    __syncthreads();
    int pin = 0;
    for (int off = 1; off < SCAN_B; off <<= 1) {
        for (int t = threadIdx.x; t < SCAN_B; t += 256) {
            int v = sm[pin][t];
            if (t >= off) v += sm[pin][t - off];
            sm[pin ^ 1][t] = v;
        }
        __syncthreads();
        pin ^= 1;
    }
    for (int t = threadIdx.x; t < SCAN_B; t += 256) {
        int idx = base + t;
        if (idx < n) excl[idx] = sm[pin][t] - in[idx];
    }
    if (threadIdx.x == 0) bsum[blockIdx.x] = sm[pin][SCAN_B - 1];
}

__global__ void scan_bsum(int* __restrict__ bsum, int nb) {
    __shared__ int sm[512];
    for (int t = threadIdx.x; t < nb; t += 256) sm[t] = bsum[t];
    __syncthreads();
    if (threadIdx.x == 0) {
        int run = 0;
        for (int i = 0; i < nb; ++i) { int v = sm[i]; sm[i] = run; run += v; }
    }
    __syncthreads();
    for (int t = threadIdx.x; t < nb; t += 256) bsum[t] = sm[t];
}

__global__ void scan_finish(int* __restrict__ rowptr, const int* __restrict__ bsum,
                            int* __restrict__ cursor, int n, int E) {
    int i = blockIdx.x * blockDim.x + threadIdx.x;
    if (i < n) {
        int v = rowptr[i] + bsum[i / SCAN_B];
        rowptr[i] = v;
        cursor[i] = v;
    }
    if (i == 0) rowptr[n] = E;
}

__global__ void fill_kernel(const int* __restrict__ src, const int* __restrict__ tgt,
                            const int* __restrict__ et, int* __restrict__ cursor,
                            int* __restrict__ es, int E) {
    int e = blockIdx.x * blockDim.x + threadIdx.x;
    if (e < E) {
        int seg = tgt[e] * RR + et[e];
        int pos = atomicAdd(&cursor[seg], 1);
        es[pos] = src[e];
    }
}

// ---------------- W packing into MFMA B-fragment order (proven) ----------------
__global__ void pack_w_kernel(const float* __restrict__ W, const float* __restrict__ root,
                              unsigned short* __restrict__ wp, int NT) {
    int tid = blockIdx.x * blockDim.x + threadIdx.x;
    int total = 9 * NT * 2048;
    if (tid >= total) return;
    int i = tid & 7;
    int lane = (tid >> 3) & 63;
    int kk = (tid >> 9) & 3;
    int t = (tid >> 11) % NT;
    int rel = (tid >> 11) / NT;
    int k = kk * 32 + ((lane >> 4) << 3) + i;
    int col = t * 16 + (lane & 15);
    int dout = NT * 16;
    float v = (rel < RR) ? W[((long)rel * DF + k) * dout + col] : root[(long)k * dout + col];
    wp[tid] = bf16r(v);
}

// ---------------- fused gather-mean + MFMA transform ----------------
// Gather restructured vs round 5: TWO edges per wave-instruction (lanes 0-31 =
// even edge, lanes 32-63 = odd edge, float4 = 16B/lane), exact per-segment
// iteration (no max-batch predication waste), es folded into one paired load.
// ~4.5x fewer vector-memory instructions on the gather path. Cross-half sum
// via __shfl_xor(32). MFMA / wp / epilogue identical to the passing round-5.
template <int NT, bool RELU>
__global__ __launch_bounds__(256) void fused_mfma_kernel(
    const float* __restrict__ x,           // [N,128] f32
    const int* __restrict__ es,            // segment-sorted src
    const int* __restrict__ rowptr,        // [N*R+1]
    const unsigned short* __restrict__ wp, // packed W frags
    const float* __restrict__ bias,        // [NT*16]
    float* __restrict__ out, int N) {
    __shared__ uint32_t a_sm[4][16][68];   // 16 rows x 136 bf16, wave-private
    const int wave = threadIdx.x >> 6;
    const int lane = threadIdx.x & 63;
    const int nb = (blockIdx.x * 4 + wave) * NPW;
    if (nb >= N) return;
    uint32_t(*A)[68] = a_sm[wave];

    for (int z = lane; z < 8 * 68; z += 64) (&A[8][0])[z] = 0u;  // rows 8..15 = 0

    const int j = lane;                    // feature-pair slot (root path)
    const int half = lane >> 5;            // 0: even edge, 1: odd edge
    const int f = lane & 31;               // feature-quad slot
    const float2* x2 = (const float2*)x;
    const float4* x4 = (const float4*)x;
    const int arow = lane & 15;
    const int ag = lane >> 4;

    f32x4 acc[NT];
#pragma unroll
    for (int t = 0; t < NT; ++t) acc[t] = (f32x4){0.f, 0.f, 0.f, 0.f};

    for (int rel = 0; rel <= RR; ++rel) {
        if (rel < RR) {
            int e0[NPW], e1[NPW];
#pragma unroll
            for (int m = 0; m < NPW; ++m) {
                int seg = (nb + m) * RR + rel;
                e0[m] = rowptr[seg];
                e1[m] = rowptr[seg + 1];
            }
#pragma unroll 2
            for (int m = 0; m < NPW; ++m) {
                f32x4 v = {0.f, 0.f, 0.f, 0.f};
                for (int e = e0[m]; e < e1[m]; e += 2) {
                    int idx = e + half;
                    idx = (idx < e1[m]) ? idx : (e1[m] - 1);
                    int s = es[idx];                 // paired load (adjacent)
                    float4 t = x4[s * 32 + f];       // 2 rows / instruction
                    bool ok = (e + half) < e1[m];
                    v.x += ok ? t.x : 0.f;
                    v.y += ok ? t.y : 0.f;
                    v.z += ok ? t.z : 0.f;
                    v.w += ok ? t.w : 0.f;
                }
                v.x += __shfl_xor(v.x, 32);
                v.y += __shfl_xor(v.y, 32);
                v.z += __shfl_xor(v.z, 32);
                v.w += __shfl_xor(v.w, 32);
                float inv = 1.f / fmaxf((float)(e1[m] - e0[m]), 1.f);
                if (half == 0) {
                    A[m][2 * f] = packbf(v.x * inv, v.y * inv);
                    A[m][2 * f + 1] = packbf(v.z * inv, v.w * inv);
                }
            }
        } else {
            // root "relation": A = raw input features
            for (int m = 0; m < NPW; ++m) {
                float2 v = x2[(nb + m) * 64 + j];
                A[m][j] = packbf(v.x, v.y);
            }
        }
        asm volatile("" ::: "memory");   // pin staging-writes before frag-reads
        sv8 af[4];                        // lane: A[arow][kk*32 + ag*8 .. +7]
#pragma unroll
        for (int kk = 0; kk < 4; ++kk)
            af[kk] = *(const sv8a*)&A[arow][kk * 16 + ag * 4];
        asm volatile("" ::: "memory");   // pin frag-reads before next staging
        const unsigned short* wr = wp + ((long)rel * NT << 11);
#pragma unroll
        for (int t = 0; t < NT; ++t) {
#pragma unroll
            for (int kk = 0; kk < 4; ++kk) {
                sv8 bf = *(const sv8a*)(wr + (((t * 4 + kk) << 9) + (lane << 3)));
                acc[t] = __builtin_amdgcn_mfma_f32_16x16x32_bf16(af[kk], bf, acc[t], 0, 0, 0);
            }
        }
    }

    // ---- epilogue: direct global stores (C/D map: col=lane&15, row=4*(lane>>4)+reg)
    constexpr int DOUT = NT * 16;
    if (lane < 32) {
#pragma unroll
        for (int t = 0; t < NT; ++t) {
            int col = t * 16 + (lane & 15);
            float bv = bias[col];
#pragma unroll
            for (int reg = 0; reg < 4; ++reg) {
                int row = ((lane >> 4) << 2) + reg;   // 0..7
                float v = acc[t][reg] + bv;
                if (RELU) v = fmaxf(v, 0.f);
                out[(long)(nb + row) * DOUT + col] = v;
            }
        }
    }
}

extern "C" void kernel_launch(void* const* d_in, const int* in_sizes, int n_in,
                              void* d_out, int out_size, void* d_ws, size_t ws_size,
                              hipStream_t stream) {
    const float* xf = (const float*)d_in[0];
    const float* W1 = (const float*)d_in[1];
    const float* r1 = (const float*)d_in[2];
    const float* b1 = (const float*)d_in[3];
    const float* W2 = (const float*)d_in[4];
    const float* r2 = (const float*)d_in[5];
    const float* b2 = (const float*)d_in[6];
    const int* eidx = (const int*)d_in[7];
    const int* etyp = (const int*)d_in[8];
    const int N = in_sizes[0] / DF;
    const int E = in_sizes[8];
    const int* src = eidx;
    const int* tgt = eidx + E;
    const int NR = N * RR;

    // ws: cnt[NR] rowptr[NR+16] cursor[NR+16] bsum[512] es[E] x1f[N*128] wp1 wp2
    int* cnt = (int*)d_ws;
    int* rowptr = cnt + NR;
    int* cursor = rowptr + NR + 16;
    int* bsum = cursor + NR + 16;
    int* es = bsum + 512;
    float* x1f = (float*)(es + E);
    unsigned short* wp1 = (unsigned short*)(x1f + (size_t)N * DF);
    unsigned short* wp2 = wp1 + 9 * 8 * 2048;

    const int nb1 = (NR + SCAN_B - 1) / SCAN_B;

    hipMemsetAsync(cnt, 0, (size_t)NR * sizeof(int), stream);
    count_kernel<<<(E + 255) / 256, 256, 0, stream>>>(tgt, etyp, cnt, E);
    scan_local<<<nb1, 256, 0, stream>>>(cnt, rowptr, bsum, NR);
    scan_bsum<<<1, 256, 0, stream>>>(bsum, nb1);
    scan_finish<<<(NR + 255) / 256, 256, 0, stream>>>(rowptr, bsum, cursor, NR, E);
    fill_kernel<<<(E + 255) / 256, 256, 0, stream>>>(src, tgt, etyp, cursor, es, E);

    pack_w_kernel<<<(9 * 8 * 2048 + 255) / 256, 256, 0, stream>>>(W1, r1, wp1, 8);
    pack_w_kernel<<<(9 * 4 * 2048 + 255) / 256, 256, 0, stream>>>(W2, r2, wp2, 4);

    const int fblocks = (N / NPW + 3) / 4;
    fused_mfma_kernel<8, true><<<fblocks, 256, 0, stream>>>(
        xf, es, rowptr, wp1, b1, x1f, N);
    fused_mfma_kernel<4, false><<<fblocks, 256, 0, stream>>>(
        x1f, es, rowptr, wp2, b2, (float*)d_out, N);
}